// Round 14
// baseline (703.672 us; speedup 1.0000x reference)
//
#include <hip/hip_runtime.h>

#define NN 512
#define DD 256

typedef float f32x4 __attribute__((ext_vector_type(4)));
typedef short s16x8 __attribute__((ext_vector_type(8)));

__device__ __forceinline__ unsigned short f2bf(float f) {
    unsigned u = __float_as_uint(f);
    u += 0x7fffu + ((u >> 16) & 1u);   // round-to-nearest-even
    return (unsigned short)(u >> 16);
}
__device__ __forceinline__ float bf2f(unsigned short s) {
    return __uint_as_float(((unsigned)s) << 16);
}
__device__ __forceinline__ unsigned packbf(float a, float b) {
    return ((unsigned)f2bf(b) << 16) | f2bf(a);
}
__device__ __forceinline__ s16x8 pack_bf(const f32x4 v0, const f32x4 v1) {
    s16x8 a;
    a[0] = (short)f2bf(v0[0]); a[1] = (short)f2bf(v0[1]);
    a[2] = (short)f2bf(v0[2]); a[3] = (short)f2bf(v0[3]);
    a[4] = (short)f2bf(v1[0]); a[5] = (short)f2bf(v1[1]);
    a[6] = (short)f2bf(v1[2]); a[7] = (short)f2bf(v1[3]);
    return a;
}
__device__ __forceinline__ void gl_lds16(const float* g, float* lds) {
    __builtin_amdgcn_global_load_lds(
        (const __attribute__((address_space(1))) void*)g,
        (__attribute__((address_space(3))) void*)lds, 16, 0, 0);
}

// ---------------------------------------------------------------------------
// K1: hb = h@W1.T + t_bias, hW2 = h@W2.T, hW4 = h@W4.T, w3b = bf16(W3),
//     zero the softmax accumulators (wacc, zacc).
// ---------------------------------------------------------------------------
__global__ __launch_bounds__(256) void k1_pre(
    const float* __restrict__ h,  const float* __restrict__ W1,
    const float* __restrict__ W2, const float* __restrict__ W4,
    const float* __restrict__ t_emb, const float* __restrict__ W_t,
    const float* __restrict__ W3,
    float* __restrict__ hb, float* __restrict__ hW2, float* __restrict__ hW4,
    unsigned short* __restrict__ w3b,
    float* __restrict__ wacc, float* __restrict__ zacc)
{
    __shared__ float xs[8][DD];
    __shared__ float st[DD];
    const int b = blockIdx.x;
    const int t = threadIdx.x;
    if (b < 64) {
        #pragma unroll
        for (int r = 0; r < 8; ++r) xs[r][t] = h[(size_t)(b * 8 + r) * DD + t];
        st[t] = t_emb[t];
        __syncthreads();
        float a1[8], a2[8], a4[8];
        #pragma unroll
        for (int r = 0; r < 8; ++r) { a1[r] = 0.f; a2[r] = 0.f; a4[r] = 0.f; }
        float tb = 0.f;
        for (int d = 0; d < DD; ++d) {
            const float w1 = W1[(size_t)t * DD + d];
            const float w2 = W2[(size_t)t * DD + d];
            const float w4 = W4[(size_t)t * DD + d];
            tb = fmaf(st[d], W_t[(size_t)t * DD + d], tb);
            #pragma unroll
            for (int r = 0; r < 8; ++r) {
                const float x = xs[r][d];
                a1[r] = fmaf(x, w1, a1[r]);
                a2[r] = fmaf(x, w2, a2[r]);
                a4[r] = fmaf(x, w4, a4[r]);
            }
        }
        #pragma unroll
        for (int r = 0; r < 8; ++r) {
            const size_t o = (size_t)(b * 8 + r) * DD + t;
            hb[o] = a1[r] + tb; hW2[o] = a2[r]; hW4[o] = a4[r];
        }
    } else if (b == 64) {
        for (int c = t; c < DD * DD / 4; c += 256) {
            const f32x4 v = *reinterpret_cast<const f32x4*>(W3 + (size_t)c * 4);
            *reinterpret_cast<uint2*>(w3b + (size_t)c * 4) =
                make_uint2(packbf(v[0], v[1]), packbf(v[2], v[3]));
        }
    } else {
        const f32x4 zero = (f32x4){0.f, 0.f, 0.f, 0.f};
        for (int c = t; c < NN * DD / 4; c += 256)
            *reinterpret_cast<f32x4*>(wacc + (size_t)c * 4) = zero;
        if (t < 256) { zacc[t] = 0.f; zacc[t + 256] = 0.f; }
    }
}

// ---------------------------------------------------------------------------
// Pure write stress: 268 MB coalesced f32 into out_e (overwritten later by
// the real k2 -> correctness preserved). Measures the achievable streaming
// write ceiling for this output pattern. Duration inferred from total-time
// arithmetic (won't be in top-5 unless writes really are ~1 TB/s).
// ---------------------------------------------------------------------------
__global__ __launch_bounds__(256) void wstress(float* __restrict__ dst,
                                               const float* __restrict__ src)
{
    const size_t bb = (size_t)blockIdx.x * 8192;
    const f32x4 v = (f32x4){src[threadIdx.x], 1.f, 2.f, 3.f};
    #pragma unroll
    for (int s = 0; s < 8; ++s)
        *reinterpret_cast<f32x4*>(dst + bb + (size_t)(s * 256 + threadIdx.x) * 4) = v;
}

// ---------------------------------------------------------------------------
// K2 body: STOP=0 real; STOP=3 full compute+epilogue, global writes/atomics
// replaced by register sums into dump (DCE guard). b masked for 2x-grid runs.
// ---------------------------------------------------------------------------
template<int STOP>
__global__ __launch_bounds__(256) void k2_tpl(
    const float* __restrict__ e,
    const unsigned short* __restrict__ w3b,
    const float* __restrict__ hb, const float* __restrict__ hW2,
    const float* __restrict__ gate_w, const float* __restrict__ gate_b,
    const float* __restrict__ ln_e_w, const float* __restrict__ ln_e_b,
    float* __restrict__ out_e,
    float* __restrict__ wacc, float* __restrict__ zacc,
    float* __restrict__ dump)
{
    const int b = blockIdx.x & 8191;
    const int row_base = b * 32;
    const int i = row_base >> 9;
    const int tid = threadIdx.x;
    const int w = tid >> 6;
    const int l = tid & 63;
    const int l15 = l & 15;
    const int lg = l >> 4;

    __shared__ __align__(16) float sAf[32 * 256];
    __shared__ unsigned short s_hbu[DD];
    __shared__ float s_lnw[DD], s_lnb[DD], s_gw[DD];
    __shared__ float s_part[32][4][2];
    __shared__ float s_glog[32][4];

    // ---- stage A via async DMA (src lane-permuted, LDS linear) ----
    {
        const float* esrc = e + (size_t)row_base * DD;
        #pragma unroll
        for (int t = 0; t < 8; ++t) {
            const int r = w * 8 + t;
            gl_lds16(esrc + (size_t)r * DD + ((l ^ (r & 7)) << 2), sAf + r * 256);
        }
    }

    const unsigned short* bp = w3b + (size_t)(w * 64 + l15) * DD + lg * 8;
    s16x8 bb[4][4];
    #pragma unroll
    for (int kk = 0; kk < 4; ++kk)
        #pragma unroll
        for (int n = 0; n < 4; ++n)
            bb[kk][n] = *reinterpret_cast<const s16x8*>(bp + (size_t)n * 16 * DD + kk * 32);

    const float gb = gate_b[0];
    s_lnw[tid] = ln_e_w[tid];
    s_lnb[tid] = ln_e_b[tid];
    s_gw[tid]  = gate_w[tid];
    s_hbu[tid] = f2bf(hb[(size_t)i * DD + tid]);
    __syncthreads();

    // ---- MFMA K-loop ----
    f32x4 acc[2][4];
    #pragma unroll
    for (int m = 0; m < 2; ++m)
        #pragma unroll
        for (int n = 0; n < 4; ++n)
            acc[m][n] = (f32x4){0.f, 0.f, 0.f, 0.f};

    #pragma unroll
    for (int kk = 0; kk < 8; ++kk) {
        s16x8 afr[2];
        #pragma unroll
        for (int m = 0; m < 2; ++m) {
            const int r = m * 16 + l15;
            const int c0 = kk * 8 + lg * 2;
            const int s0 = c0 ^ (r & 7);
            const int s1 = (c0 + 1) ^ (r & 7);
            const f32x4 v0 = *reinterpret_cast<const f32x4*>(sAf + r * 256 + s0 * 4);
            const f32x4 v1 = *reinterpret_cast<const f32x4*>(sAf + r * 256 + s1 * 4);
            afr[m] = pack_bf(v0, v1);
        }
        #pragma unroll
        for (int n = 0; n < 4; ++n)
            #pragma unroll
            for (int m = 0; m < 2; ++m)
                acc[m][n] = __builtin_amdgcn_mfma_f32_16x16x32_bf16(afr[m], bb[kk & 3][n], acc[m][n], 0, 0, 0);
        if (kk < 4) {
            #pragma unroll
            for (int n = 0; n < 4; ++n)
                bb[kk & 3][n] = *reinterpret_cast<const s16x8*>(bp + (size_t)n * 16 * DD + (kk + 4) * 32);
        }
    }

    // ---- epilogue A ----
    float hbn[4];
    #pragma unroll
    for (int n = 0; n < 4; ++n) hbn[n] = bf2f(s_hbu[w * 64 + n * 16 + l15]);

    #pragma unroll
    for (int m = 0; m < 2; ++m) {
        #pragma unroll
        for (int q = 0; q < 4; ++q) {
            const int r = m * 16 + lg * 4 + q;
            const int j = (row_base + r) & 511;
            const float* h2p = hW2 + (size_t)j * DD + w * 64 + l15;
            float s1 = 0.f, s2 = 0.f;
            #pragma unroll
            for (int n = 0; n < 4; ++n) {
                const float v = acc[m][n][q] + hbn[n] + h2p[n * 16];
                acc[m][n][q] = v;
                s1 += v;
                s2 = fmaf(v, v, s2);
            }
            #pragma unroll
            for (int s = 1; s < 16; s <<= 1) {
                s1 += __shfl_xor(s1, s, 64);
                s2 += __shfl_xor(s2, s, 64);
            }
            if (l15 == 0) { s_part[r][w][0] = s1; s_part[r][w][1] = s2; }
        }
    }
    __syncthreads();

    // ---- epilogue B ----
    float vdump = 0.f;
    #pragma unroll
    for (int m = 0; m < 2; ++m) {
        #pragma unroll
        for (int q = 0; q < 4; ++q) {
            const int r = m * 16 + lg * 4 + q;
            float S1 = 0.f, S2 = 0.f;
            #pragma unroll
            for (int ww = 0; ww < 4; ++ww) { S1 += s_part[r][ww][0]; S2 += s_part[r][ww][1]; }
            const float mu = S1 * (1.f / 256.f);
            const float rs = rsqrtf(S2 * (1.f / 256.f) - mu * mu + 1e-5f);
            const size_t rowg = (size_t)(row_base + r);
            float gl = 0.f;
            #pragma unroll
            for (int n = 0; n < 4; ++n) {
                const int c = w * 64 + n * 16 + l15;
                float v = (acc[m][n][q] - mu) * rs * s_lnw[c] + s_lnb[c];
                v = fmaxf(v, 0.f);
                acc[m][n][q] = v;
                if (STOP == 0) out_e[rowg * DD + c] = v; else vdump += v;
                gl = fmaf(v, s_gw[c], gl);
            }
            #pragma unroll
            for (int s = 1; s < 16; s <<= 1) gl += __shfl_xor(gl, s, 64);
            if (l15 == 0) s_glog[r][w] = gl;
        }
    }
    __syncthreads();

    // ---- fused no-max softmax partials ----
    float p[4] = {0.f, 0.f, 0.f, 0.f};
    float zl = 0.f;
    #pragma unroll
    for (int m = 0; m < 2; ++m) {
        #pragma unroll
        for (int q = 0; q < 4; ++q) {
            const int r = m * 16 + lg * 4 + q;
            const float lv = gb + s_glog[r][0] + s_glog[r][1] + s_glog[r][2] + s_glog[r][3];
            const float ex = __expf(lv);
            zl += ex;
            #pragma unroll
            for (int n = 0; n < 4; ++n) p[n] = fmaf(ex, acc[m][n][q], p[n]);
        }
    }
    #pragma unroll
    for (int n = 0; n < 4; ++n) {
        p[n] += __shfl_xor(p[n], 16, 64);
        p[n] += __shfl_xor(p[n], 32, 64);
    }
    zl += __shfl_xor(zl, 16, 64);
    zl += __shfl_xor(zl, 32, 64);

    if (STOP == 0) {
        if (lg == 0) {
            #pragma unroll
            for (int n = 0; n < 4; ++n)
                atomicAdd(&wacc[(size_t)i * DD + w * 64 + n * 16 + l15], p[n]);
        }
        if (w == 0 && l == 0) atomicAdd(&zacc[i], zl);
    } else {
        vdump += zl + p[0] + p[1] + p[2] + p[3];
        dump[(((int)blockIdx.x & 255) << 8) | tid] = vdump;
    }
}

// ---------------------------------------------------------------------------
// K4: h_new = h + relu(LN(hW4 + (wacc/z)@W5.T))
// ---------------------------------------------------------------------------
__global__ __launch_bounds__(256) void k4_final(
    const float* __restrict__ wacc, const float* __restrict__ zacc,
    const float* __restrict__ W5,
    const float* __restrict__ hW4, const float* __restrict__ h,
    const float* __restrict__ ln_h_w, const float* __restrict__ ln_h_b,
    float* __restrict__ out_h)
{
    const int i = blockIdx.x;
    const int k = threadIdx.x;
    __shared__ float xs[DD];
    __shared__ float red[256];

    const float zinv = 1.f / zacc[i];
    xs[k] = wacc[(size_t)i * DD + k] * zinv;
    __syncthreads();
    float a = 0.f;
    for (int d = 0; d < DD; ++d) a = fmaf(xs[d], W5[(size_t)k * DD + d], a);
    const float p = hW4[(size_t)i * DD + k] + a;

    red[k] = p;
    __syncthreads();
    for (int s = 128; s > 0; s >>= 1) {
        if (k < s) red[k] += red[k + s];
        __syncthreads();
    }
    const float mu = red[0] * (1.f / 256.f);
    __syncthreads();
    const float d0 = p - mu;
    red[k] = d0 * d0;
    __syncthreads();
    for (int s = 128; s > 0; s >>= 1) {
        if (k < s) red[k] += red[k + s];
        __syncthreads();
    }
    const float rs = rsqrtf(red[0] * (1.f / 256.f) + 1e-5f);
    float v = d0 * rs * ln_h_w[k] + ln_h_b[k];
    v = fmaxf(v, 0.f);
    out_h[(size_t)i * DD + k] = h[(size_t)i * DD + k] + v;
}

// ---------------------------------------------------------------------------
extern "C" void kernel_launch(void* const* d_in, const int* in_sizes, int n_in,
                              void* d_out, int out_size, void* d_ws, size_t ws_size,
                              hipStream_t stream)
{
    const float* h      = (const float*)d_in[0];
    const float* e      = (const float*)d_in[1];
    const float* t_emb  = (const float*)d_in[2];
    const float* W1     = (const float*)d_in[3];
    const float* W2     = (const float*)d_in[4];
    const float* W3     = (const float*)d_in[5];
    const float* W_t    = (const float*)d_in[6];
    const float* W4     = (const float*)d_in[7];
    const float* W5     = (const float*)d_in[8];
    const float* gate_w = (const float*)d_in[9];
    const float* gate_b = (const float*)d_in[10];
    const float* ln_e_w = (const float*)d_in[11];
    const float* ln_e_b = (const float*)d_in[12];
    const float* ln_h_w = (const float*)d_in[13];
    const float* ln_h_b = (const float*)d_in[14];

    float* out_h = (float*)d_out;
    float* out_e = out_h + NN * DD;

    // workspace layout (~2.6 MiB)
    float* wsf  = (float*)d_ws;
    float* hb   = wsf;                        // 131072 (hW1 + t_bias)
    float* hW2  = hb + NN * DD;               // 131072
    float* hW4  = hW2 + NN * DD;              // 131072
    float* wacc = hW4 + NN * DD;              // 131072
    float* zacc = wacc + NN * DD;             // 512
    unsigned short* w3b = (unsigned short*)(zacc + NN);  // 65536 ushort
    float* dump = (float*)(w3b + DD * DD);    // 65536 floats

    k1_pre<<<66, 256, 0, stream>>>(h, W1, W2, W4, t_emb, W_t, W3,
                                   hb, hW2, hW4, w3b, wacc, zacc);
    // probe 1: pure coalesced write of 268 MB into out_e (overwritten below)
    wstress<<<8192, 256, 0, stream>>>(out_e, h);
    // probe 2: full compute, no global-output writes, 2x grid (top-5 visible)
    k2_tpl<3><<<16384, 256, 0, stream>>>(e, w3b, hb, hW2, gate_w, gate_b,
                                         ln_e_w, ln_e_b, out_e, wacc, zacc, dump);
    // real pipeline
    k2_tpl<0><<<8192, 256, 0, stream>>>(e, w3b, hb, hW2, gate_w, gate_b,
                                        ln_e_w, ln_e_b, out_e, wacc, zacc, dump);
    k4_final<<<512, 256, 0, stream>>>(wacc, zacc, W5, hW4, h,
                                      ln_h_w, ln_h_b, out_h);
}

// Round 15
// 407.974 us; speedup vs baseline: 1.7248x; 1.7248x over previous
//
#include <hip/hip_runtime.h>

#define NN 512
#define DD 256

typedef float f32x4 __attribute__((ext_vector_type(4)));
typedef short s16x8 __attribute__((ext_vector_type(8)));

__device__ __forceinline__ unsigned short f2bf(float f) {
    unsigned u = __float_as_uint(f);
    u += 0x7fffu + ((u >> 16) & 1u);   // round-to-nearest-even
    return (unsigned short)(u >> 16);
}
__device__ __forceinline__ float bf2f(unsigned short s) {
    return __uint_as_float(((unsigned)s) << 16);
}
__device__ __forceinline__ unsigned packbf(float a, float b) {
    return ((unsigned)f2bf(b) << 16) | f2bf(a);
}
__device__ __forceinline__ s16x8 pack_bf(const f32x4 v0, const f32x4 v1) {
    s16x8 a;
    a[0] = (short)f2bf(v0[0]); a[1] = (short)f2bf(v0[1]);
    a[2] = (short)f2bf(v0[2]); a[3] = (short)f2bf(v0[3]);
    a[4] = (short)f2bf(v1[0]); a[5] = (short)f2bf(v1[1]);
    a[6] = (short)f2bf(v1[2]); a[7] = (short)f2bf(v1[3]);
    return a;
}
__device__ __forceinline__ void gl_lds16(const float* g, float* lds) {
    __builtin_amdgcn_global_load_lds(
        (const __attribute__((address_space(1))) void*)g,
        (__attribute__((address_space(3))) void*)lds, 16, 0, 0);
}

// LDS-only barrier: does NOT drain vmcnt (keeps DMA in flight across it).
#define LDS_SYNC() do {                                          \
    asm volatile("s_waitcnt lgkmcnt(0)" ::: "memory");           \
    __builtin_amdgcn_s_barrier();                                \
    __builtin_amdgcn_sched_barrier(0);                           \
} while (0)

// ---------------------------------------------------------------------------
// K1: hb = h@W1.T + t_bias, hW2 = h@W2.T, hW4 = h@W4.T, w3b = bf16(W3),
//     zero the softmax accumulators (wacc, zacc).
// ---------------------------------------------------------------------------
__global__ __launch_bounds__(256) void k1_pre(
    const float* __restrict__ h,  const float* __restrict__ W1,
    const float* __restrict__ W2, const float* __restrict__ W4,
    const float* __restrict__ t_emb, const float* __restrict__ W_t,
    const float* __restrict__ W3,
    float* __restrict__ hb, float* __restrict__ hW2, float* __restrict__ hW4,
    unsigned short* __restrict__ w3b,
    float* __restrict__ wacc, float* __restrict__ zacc)
{
    __shared__ float xs[8][DD];
    __shared__ float st[DD];
    const int b = blockIdx.x;
    const int t = threadIdx.x;
    if (b < 64) {
        #pragma unroll
        for (int r = 0; r < 8; ++r) xs[r][t] = h[(size_t)(b * 8 + r) * DD + t];
        st[t] = t_emb[t];
        __syncthreads();
        float a1[8], a2[8], a4[8];
        #pragma unroll
        for (int r = 0; r < 8; ++r) { a1[r] = 0.f; a2[r] = 0.f; a4[r] = 0.f; }
        float tb = 0.f;
        for (int d = 0; d < DD; ++d) {
            const float w1 = W1[(size_t)t * DD + d];
            const float w2 = W2[(size_t)t * DD + d];
            const float w4 = W4[(size_t)t * DD + d];
            tb = fmaf(st[d], W_t[(size_t)t * DD + d], tb);
            #pragma unroll
            for (int r = 0; r < 8; ++r) {
                const float x = xs[r][d];
                a1[r] = fmaf(x, w1, a1[r]);
                a2[r] = fmaf(x, w2, a2[r]);
                a4[r] = fmaf(x, w4, a4[r]);
            }
        }
        #pragma unroll
        for (int r = 0; r < 8; ++r) {
            const size_t o = (size_t)(b * 8 + r) * DD + t;
            hb[o] = a1[r] + tb; hW2[o] = a2[r]; hW4[o] = a4[r];
        }
    } else if (b == 64) {
        for (int c = t; c < DD * DD / 4; c += 256) {
            const f32x4 v = *reinterpret_cast<const f32x4*>(W3 + (size_t)c * 4);
            *reinterpret_cast<uint2*>(w3b + (size_t)c * 4) =
                make_uint2(packbf(v[0], v[1]), packbf(v[2], v[3]));
        }
    } else {
        const f32x4 zero = (f32x4){0.f, 0.f, 0.f, 0.f};
        for (int c = t; c < NN * DD / 4; c += 256)
            *reinterpret_cast<f32x4*>(wacc + (size_t)c * 4) = zero;
        if (t < 256) { zacc[t] = 0.f; zacc[t + 256] = 0.f; }
    }
}

// ---------------------------------------------------------------------------
// K2: R12 body + 4-tile DMA double-buffer pipeline (T3/T4 counted vmcnt).
// Block = 128 rows (same i) = 4 tiles x 32 rows, two 32KB LDS bufs.
// DMA for tile t+2 issued at END of iter t (after all of iter t's VMEM ops
// -> vmcnt(8) leaves exactly those 8 outstanding); intra-loop barriers are
// lgkmcnt-only raw s_barrier (never drain the DMA). DMA uses no VGPRs ->
// no spill risk (the R5/R6/R11 killer). Softmax p/z accumulated in regs
// across tiles -> one atomicAdd set per block.
// ---------------------------------------------------------------------------
__global__ __launch_bounds__(256) void k2_big(
    const float* __restrict__ e,
    const unsigned short* __restrict__ w3b,
    const float* __restrict__ hb, const float* __restrict__ hW2,
    const float* __restrict__ gate_w, const float* __restrict__ gate_b,
    const float* __restrict__ ln_e_w, const float* __restrict__ ln_e_b,
    float* __restrict__ out_e,
    float* __restrict__ wacc, float* __restrict__ zacc)
{
    const int blk = blockIdx.x;
    const int row0 = blk * 128;               // 4 tiles x 32 rows, same i
    const int i = row0 >> 9;
    const int tid = threadIdx.x;
    const int w = tid >> 6;
    const int l = tid & 63;
    const int l15 = l & 15;
    const int lg = l >> 4;

    __shared__ __align__(16) float sAf[2][32 * 256];   // 2 x 32 KiB
    __shared__ unsigned short s_hbu[DD];
    __shared__ float s_lnw[DD], s_lnb[DD], s_gw[DD];
    __shared__ float s_part[32][4][2];
    __shared__ float s_glog[32][4];

    // ---- DMA issue for tile tt into buffer bufsel (8 gl_lds per wave) ----
    auto issue_dma = [&](int tt, int bufsel) {
        const float* esrc = e + (size_t)(row0 + tt * 32) * DD;
        #pragma unroll
        for (int t8 = 0; t8 < 8; ++t8) {
            const int r = w * 8 + t8;
            gl_lds16(esrc + (size_t)r * DD + ((l ^ (r & 7)) << 2),
                     &sAf[bufsel][r * 256]);
        }
    };

    // ---- prologue: DMA tile0 -> tables -> DMA tile1; wait tile0 only ----
    issue_dma(0, 0);
    s_lnw[tid] = ln_e_w[tid];
    s_lnb[tid] = ln_e_b[tid];
    s_gw[tid]  = gate_w[tid];
    s_hbu[tid] = f2bf(hb[(size_t)i * DD + tid]);
    const float gb = gate_b[0];
    issue_dma(1, 1);
    asm volatile("s_waitcnt vmcnt(8) lgkmcnt(0)" ::: "memory");
    __builtin_amdgcn_s_barrier();
    __builtin_amdgcn_sched_barrier(0);

    const unsigned short* bp = w3b + (size_t)(w * 64 + l15) * DD + lg * 8;

    float p[4] = {0.f, 0.f, 0.f, 0.f};
    float zl = 0.f;
    float hbn[4];
    #pragma unroll
    for (int n = 0; n < 4; ++n) hbn[n] = bf2f(s_hbu[w * 64 + n * 16 + l15]);

    #pragma unroll
    for (int t = 0; t < 4; ++t) {
        const int cur = t & 1;
        const int row_base = row0 + t * 32;
        const float* sA = sAf[cur];

        // ---- B: 4 K-slot fragments (depth-4 prefetch base, L2-hot) ----
        s16x8 bb[4][4];
        #pragma unroll
        for (int kk = 0; kk < 4; ++kk)
            #pragma unroll
            for (int n = 0; n < 4; ++n)
                bb[kk][n] = *reinterpret_cast<const s16x8*>(bp + (size_t)n * 16 * DD + kk * 32);

        // ---- MFMA K-loop: A from LDS (permuted slots) + cvt at assembly ----
        f32x4 acc[2][4];
        #pragma unroll
        for (int m = 0; m < 2; ++m)
            #pragma unroll
            for (int n = 0; n < 4; ++n)
                acc[m][n] = (f32x4){0.f, 0.f, 0.f, 0.f};

        #pragma unroll
        for (int kk = 0; kk < 8; ++kk) {
            s16x8 afr[2];
            #pragma unroll
            for (int m = 0; m < 2; ++m) {
                const int r = m * 16 + l15;
                const int c0 = kk * 8 + lg * 2;
                const int s0 = c0 ^ (r & 7);
                const int s1 = (c0 + 1) ^ (r & 7);
                const f32x4 v0 = *reinterpret_cast<const f32x4*>(sA + r * 256 + s0 * 4);
                const f32x4 v1 = *reinterpret_cast<const f32x4*>(sA + r * 256 + s1 * 4);
                afr[m] = pack_bf(v0, v1);
            }
            #pragma unroll
            for (int n = 0; n < 4; ++n)
                #pragma unroll
                for (int m = 0; m < 2; ++m)
                    acc[m][n] = __builtin_amdgcn_mfma_f32_16x16x32_bf16(afr[m], bb[kk & 3][n], acc[m][n], 0, 0, 0);
            if (kk < 4) {
                #pragma unroll
                for (int n = 0; n < 4; ++n)
                    bb[kk & 3][n] = *reinterpret_cast<const s16x8*>(bp + (size_t)n * 16 * DD + (kk + 4) * 32);
            }
        }

        // ---- epilogue A: biases (hW2 from L2) + LN partial sums ----
        #pragma unroll
        for (int m = 0; m < 2; ++m) {
            #pragma unroll
            for (int q = 0; q < 4; ++q) {
                const int r = m * 16 + lg * 4 + q;
                const int j = (row_base + r) & 511;
                const float* h2p = hW2 + (size_t)j * DD + w * 64 + l15;
                float s1 = 0.f, s2 = 0.f;
                #pragma unroll
                for (int n = 0; n < 4; ++n) {
                    const float v = acc[m][n][q] + hbn[n] + h2p[n * 16];
                    acc[m][n][q] = v;
                    s1 += v;
                    s2 = fmaf(v, v, s2);
                }
                #pragma unroll
                for (int s = 1; s < 16; s <<= 1) {
                    s1 += __shfl_xor(s1, s, 64);
                    s2 += __shfl_xor(s2, s, 64);
                }
                if (l15 == 0) { s_part[r][w][0] = s1; s_part[r][w][1] = s2; }
            }
        }
        LDS_SYNC();   // all waves past K-loop reads of sA; s_part visible

        // ---- epilogue B: stats, normalize, relu, store, gate partials ----
        #pragma unroll
        for (int m = 0; m < 2; ++m) {
            #pragma unroll
            for (int q = 0; q < 4; ++q) {
                const int r = m * 16 + lg * 4 + q;
                float S1 = 0.f, S2 = 0.f;
                #pragma unroll
                for (int ww = 0; ww < 4; ++ww) { S1 += s_part[r][ww][0]; S2 += s_part[r][ww][1]; }
                const float mu = S1 * (1.f / 256.f);
                const float rs = rsqrtf(S2 * (1.f / 256.f) - mu * mu + 1e-5f);
                const size_t rowg = (size_t)(row_base + r);
                float gl = 0.f;
                #pragma unroll
                for (int n = 0; n < 4; ++n) {
                    const int c = w * 64 + n * 16 + l15;
                    float v = (acc[m][n][q] - mu) * rs * s_lnw[c] + s_lnb[c];
                    v = fmaxf(v, 0.f);
                    acc[m][n][q] = v;
                    out_e[rowg * DD + c] = v;
                    gl = fmaf(v, s_gw[c], gl);
                }
                #pragma unroll
                for (int s = 1; s < 16; s <<= 1) gl += __shfl_xor(gl, s, 64);
                if (l15 == 0) s_glog[r][w] = gl;
            }
        }
        LDS_SYNC();   // s_glog visible

        // ---- softmax partials (accumulated across tiles; same i) ----
        #pragma unroll
        for (int m = 0; m < 2; ++m) {
            #pragma unroll
            for (int q = 0; q < 4; ++q) {
                const int r = m * 16 + lg * 4 + q;
                const float lv = gb + s_glog[r][0] + s_glog[r][1] + s_glog[r][2] + s_glog[r][3];
                const float ex = __expf(lv);
                zl += ex;
                #pragma unroll
                for (int n = 0; n < 4; ++n) p[n] = fmaf(ex, acc[m][n][q], p[n]);
            }
        }

        // ---- end of iter: issue DMA(t+2) LAST (newest VMEM ops), then
        //      counted wait: vmcnt(8) leaves exactly those 8 in flight ----
        if (t < 2) issue_dma(t + 2, cur);
        if (t == 0 || t == 1) {
            asm volatile("s_waitcnt vmcnt(8) lgkmcnt(0)" ::: "memory");
            __builtin_amdgcn_s_barrier();
            __builtin_amdgcn_sched_barrier(0);
        } else if (t == 2) {
            asm volatile("s_waitcnt vmcnt(0) lgkmcnt(0)" ::: "memory");
            __builtin_amdgcn_s_barrier();
            __builtin_amdgcn_sched_barrier(0);
        }
    }

    // ---- block tail: reduce p,z over lg and atomically combine (4 blocks/i) ----
    #pragma unroll
    for (int n = 0; n < 4; ++n) {
        p[n] += __shfl_xor(p[n], 16, 64);
        p[n] += __shfl_xor(p[n], 32, 64);
    }
    zl += __shfl_xor(zl, 16, 64);
    zl += __shfl_xor(zl, 32, 64);
    if (lg == 0) {
        #pragma unroll
        for (int n = 0; n < 4; ++n)
            atomicAdd(&wacc[(size_t)i * DD + w * 64 + n * 16 + l15], p[n]);
    }
    if (w == 0 && l == 0) atomicAdd(&zacc[i], zl);
}

// ---------------------------------------------------------------------------
// K4: h_new = h + relu(LN(hW4 + (wacc/z)@W5.T))
// ---------------------------------------------------------------------------
__global__ __launch_bounds__(256) void k4_final(
    const float* __restrict__ wacc, const float* __restrict__ zacc,
    const float* __restrict__ W5,
    const float* __restrict__ hW4, const float* __restrict__ h,
    const float* __restrict__ ln_h_w, const float* __restrict__ ln_h_b,
    float* __restrict__ out_h)
{
    const int i = blockIdx.x;
    const int k = threadIdx.x;
    __shared__ float xs[DD];
    __shared__ float red[256];

    const float zinv = 1.f / zacc[i];
    xs[k] = wacc[(size_t)i * DD + k] * zinv;
    __syncthreads();
    float a = 0.f;
    for (int d = 0; d < DD; ++d) a = fmaf(xs[d], W5[(size_t)k * DD + d], a);
    const float p = hW4[(size_t)i * DD + k] + a;

    red[k] = p;
    __syncthreads();
    for (int s = 128; s > 0; s >>= 1) {
        if (k < s) red[k] += red[k + s];
        __syncthreads();
    }
    const float mu = red[0] * (1.f / 256.f);
    __syncthreads();
    const float d0 = p - mu;
    red[k] = d0 * d0;
    __syncthreads();
    for (int s = 128; s > 0; s >>= 1) {
        if (k < s) red[k] += red[k + s];
        __syncthreads();
    }
    const float rs = rsqrtf(red[0] * (1.f / 256.f) + 1e-5f);
    float v = d0 * rs * ln_h_w[k] + ln_h_b[k];
    v = fmaxf(v, 0.f);
    out_h[(size_t)i * DD + k] = h[(size_t)i * DD + k] + v;
}

// ---------------------------------------------------------------------------
extern "C" void kernel_launch(void* const* d_in, const int* in_sizes, int n_in,
                              void* d_out, int out_size, void* d_ws, size_t ws_size,
                              hipStream_t stream)
{
    const float* h      = (const float*)d_in[0];
    const float* e      = (const float*)d_in[1];
    const float* t_emb  = (const float*)d_in[2];
    const float* W1     = (const float*)d_in[3];
    const float* W2     = (const float*)d_in[4];
    const float* W3     = (const float*)d_in[5];
    const float* W_t    = (const float*)d_in[6];
    const float* W4     = (const float*)d_in[7];
    const float* W5     = (const float*)d_in[8];
    const float* gate_w = (const float*)d_in[9];
    const float* gate_b = (const float*)d_in[10];
    const float* ln_e_w = (const float*)d_in[11];
    const float* ln_e_b = (const float*)d_in[12];
    const float* ln_h_w = (const float*)d_in[13];
    const float* ln_h_b = (const float*)d_in[14];

    float* out_h = (float*)d_out;
    float* out_e = out_h + NN * DD;

    // workspace layout (~2.3 MiB)
    float* wsf  = (float*)d_ws;
    float* hb   = wsf;                        // 131072 (hW1 + t_bias)
    float* hW2  = hb + NN * DD;               // 131072
    float* hW4  = hW2 + NN * DD;              // 131072
    float* wacc = hW4 + NN * DD;              // 131072
    float* zacc = wacc + NN * DD;             // 512
    unsigned short* w3b = (unsigned short*)(zacc + NN);  // 65536 ushort

    k1_pre<<<66, 256, 0, stream>>>(h, W1, W2, W4, t_emb, W_t, W3,
                                   hb, hW2, hW4, w3b, wacc, zacc);
    k2_big<<<2048, 256, 0, stream>>>(e, w3b, hb, hW2, gate_w, gate_b,
                                     ln_e_w, ln_e_b, out_e, wacc, zacc);
    k4_final<<<512, 256, 0, stream>>>(wacc, zacc, W5, hW4, h,
                                      ln_h_w, ln_h_b, out_h);
}

// Round 16
// 322.016 us; speedup vs baseline: 2.1852x; 1.2669x over previous
//
#include <hip/hip_runtime.h>

#define NN 512
#define DD 256

typedef float f32x4 __attribute__((ext_vector_type(4)));
typedef short s16x8 __attribute__((ext_vector_type(8)));

__device__ __forceinline__ unsigned short f2bf(float f) {
    unsigned u = __float_as_uint(f);
    u += 0x7fffu + ((u >> 16) & 1u);   // round-to-nearest-even
    return (unsigned short)(u >> 16);
}
__device__ __forceinline__ float bf2f(unsigned short s) {
    return __uint_as_float(((unsigned)s) << 16);
}
__device__ __forceinline__ unsigned packbf(float a, float b) {
    return ((unsigned)f2bf(b) << 16) | f2bf(a);
}
__device__ __forceinline__ s16x8 pack_bf(const f32x4 v0, const f32x4 v1) {
    s16x8 a;
    a[0] = (short)f2bf(v0[0]); a[1] = (short)f2bf(v0[1]);
    a[2] = (short)f2bf(v0[2]); a[3] = (short)f2bf(v0[3]);
    a[4] = (short)f2bf(v1[0]); a[5] = (short)f2bf(v1[1]);
    a[6] = (short)f2bf(v1[2]); a[7] = (short)f2bf(v1[3]);
    return a;
}
__device__ __forceinline__ void gl_lds16(const float* g, float* lds) {
    __builtin_amdgcn_global_load_lds(
        (const __attribute__((address_space(1))) void*)g,
        (__attribute__((address_space(3))) void*)lds, 16, 0, 0);
}

// LDS-only barrier: does NOT drain vmcnt (keeps DMA in flight). R15-verified.
#define LDS_SYNC() do {                                          \
    asm volatile("s_waitcnt lgkmcnt(0)" ::: "memory");           \
    __builtin_amdgcn_s_barrier();                                \
    __builtin_amdgcn_sched_barrier(0);                           \
} while (0)

// ---------------------------------------------------------------------------
// K1: hb = h@W1.T + t_bias, hW2 = h@W2.T, hW4 = h@W4.T, w3b = bf16(W3),
//     zero the softmax accumulators (wacc, zacc).
// ---------------------------------------------------------------------------
__global__ __launch_bounds__(256) void k1_pre(
    const float* __restrict__ h,  const float* __restrict__ W1,
    const float* __restrict__ W2, const float* __restrict__ W4,
    const float* __restrict__ t_emb, const float* __restrict__ W_t,
    const float* __restrict__ W3,
    float* __restrict__ hb, float* __restrict__ hW2, float* __restrict__ hW4,
    unsigned short* __restrict__ w3b,
    float* __restrict__ wacc, float* __restrict__ zacc)
{
    __shared__ float xs[8][DD];
    __shared__ float st[DD];
    const int b = blockIdx.x;
    const int t = threadIdx.x;
    if (b < 64) {
        #pragma unroll
        for (int r = 0; r < 8; ++r) xs[r][t] = h[(size_t)(b * 8 + r) * DD + t];
        st[t] = t_emb[t];
        __syncthreads();
        float a1[8], a2[8], a4[8];
        #pragma unroll
        for (int r = 0; r < 8; ++r) { a1[r] = 0.f; a2[r] = 0.f; a4[r] = 0.f; }
        float tb = 0.f;
        for (int d = 0; d < DD; ++d) {
            const float w1 = W1[(size_t)t * DD + d];
            const float w2 = W2[(size_t)t * DD + d];
            const float w4 = W4[(size_t)t * DD + d];
            tb = fmaf(st[d], W_t[(size_t)t * DD + d], tb);
            #pragma unroll
            for (int r = 0; r < 8; ++r) {
                const float x = xs[r][d];
                a1[r] = fmaf(x, w1, a1[r]);
                a2[r] = fmaf(x, w2, a2[r]);
                a4[r] = fmaf(x, w4, a4[r]);
            }
        }
        #pragma unroll
        for (int r = 0; r < 8; ++r) {
            const size_t o = (size_t)(b * 8 + r) * DD + t;
            hb[o] = a1[r] + tb; hW2[o] = a2[r]; hW4[o] = a4[r];
        }
    } else if (b == 64) {
        for (int c = t; c < DD * DD / 4; c += 256) {
            const f32x4 v = *reinterpret_cast<const f32x4*>(W3 + (size_t)c * 4);
            *reinterpret_cast<uint2*>(w3b + (size_t)c * 4) =
                make_uint2(packbf(v[0], v[1]), packbf(v[2], v[3]));
        }
    } else {
        const f32x4 zero = (f32x4){0.f, 0.f, 0.f, 0.f};
        for (int c = t; c < NN * DD / 4; c += 256)
            *reinterpret_cast<f32x4*>(wacc + (size_t)c * 4) = zero;
        if (t < 256) { zacc[t] = 0.f; zacc[t + 256] = 0.f; }
    }
}

// ---------------------------------------------------------------------------
// K2: R12 body, block = 32 rows split into 2x16-row tiles, BOTH tile DMAs
// issued in the prologue (tile1 flies under tile0's whole compute).
// Internal barriers = LDS_SYNC (lgkm-only, never drain DMA); single
// __syncthreads() at the tile boundary (only fresh stores outstanding).
// acc[1][4] (16 AGPR), no cross-phase prefetch regs -> ~90 regs, 37KB LDS
// -> up to 4 blocks/CU. p/z accumulated across both tiles (1 atomic set).
// ---------------------------------------------------------------------------
__global__ __launch_bounds__(256) void k2_big(
    const float* __restrict__ e,
    const unsigned short* __restrict__ w3b,
    const float* __restrict__ hb, const float* __restrict__ hW2,
    const float* __restrict__ gate_w, const float* __restrict__ gate_b,
    const float* __restrict__ ln_e_w, const float* __restrict__ ln_e_b,
    float* __restrict__ out_e,
    float* __restrict__ wacc, float* __restrict__ zacc)
{
    const int blk = blockIdx.x;
    const int row0 = blk * 32;                // 2 tiles x 16 rows, same i
    const int i = row0 >> 9;
    const int tid = threadIdx.x;
    const int w = tid >> 6;
    const int l = tid & 63;
    const int l15 = l & 15;
    const int lg = l >> 4;

    __shared__ __align__(16) float sAf[2][16 * 256];   // 2 x 16 KiB f32
    __shared__ unsigned short s_hbu[DD];
    __shared__ float s_lnw[DD], s_lnb[DD], s_gw[DD];
    __shared__ float s_part[16][4][2];
    __shared__ float s_glog[16][4];

    // ---- prologue: DMA BOTH tiles (wave w stages rows w*4..w*4+3 of each;
    //      src lane-permuted chunk = l ^ (r&7), LDS linear — R12 pattern) ----
    {
        const float* esrc = e + (size_t)row0 * DD;
        #pragma unroll
        for (int t4 = 0; t4 < 4; ++t4) {
            const int r = w * 4 + t4;
            gl_lds16(esrc + (size_t)r * DD + ((l ^ (r & 7)) << 2), &sAf[0][r * 256]);
        }
        #pragma unroll
        for (int t4 = 0; t4 < 4; ++t4) {
            const int r = w * 4 + t4;
            gl_lds16(esrc + (size_t)(16 + r) * DD + ((l ^ (r & 7)) << 2), &sAf[1][r * 256]);
        }
    }
    s_lnw[tid] = ln_e_w[tid];
    s_lnb[tid] = ln_e_b[tid];
    s_gw[tid]  = gate_w[tid];
    s_hbu[tid] = f2bf(hb[(size_t)i * DD + tid]);
    const float gb = gate_b[0];
    // wait tile0 only: newest 4 VMEM ops (tile1 DMA) stay in flight.
    asm volatile("s_waitcnt vmcnt(4) lgkmcnt(0)" ::: "memory");
    __builtin_amdgcn_s_barrier();
    __builtin_amdgcn_sched_barrier(0);

    const unsigned short* bp = w3b + (size_t)(w * 64 + l15) * DD + lg * 8;
    float hbn[4];
    #pragma unroll
    for (int n = 0; n < 4; ++n) hbn[n] = bf2f(s_hbu[w * 64 + n * 16 + l15]);

    float p[4] = {0.f, 0.f, 0.f, 0.f};
    float zl = 0.f;

    for (int t = 0; t < 2; ++t) {
        if (t == 1) __syncthreads();          // tile1 DMA long done; drains stores
        const int row_base = row0 + t * 16;
        const float* sA = sAf[t];

        // ---- B: 4 K-slot fragments (depth-4 prefetch base, L2-hot) ----
        s16x8 bb[4][4];
        #pragma unroll
        for (int kk = 0; kk < 4; ++kk)
            #pragma unroll
            for (int n = 0; n < 4; ++n)
                bb[kk][n] = *reinterpret_cast<const s16x8*>(bp + (size_t)n * 16 * DD + kk * 32);

        // ---- MFMA K-loop: A row = l15 (16-row tile), cvt at assembly ----
        f32x4 acc[4];
        #pragma unroll
        for (int n = 0; n < 4; ++n) acc[n] = (f32x4){0.f, 0.f, 0.f, 0.f};

        #pragma unroll
        for (int kk = 0; kk < 8; ++kk) {
            const int c0 = kk * 8 + lg * 2;
            const int s0 = c0 ^ (l15 & 7);
            const int s1 = (c0 + 1) ^ (l15 & 7);
            const f32x4 v0 = *reinterpret_cast<const f32x4*>(sA + l15 * 256 + s0 * 4);
            const f32x4 v1 = *reinterpret_cast<const f32x4*>(sA + l15 * 256 + s1 * 4);
            const s16x8 afr = pack_bf(v0, v1);
            #pragma unroll
            for (int n = 0; n < 4; ++n)
                acc[n] = __builtin_amdgcn_mfma_f32_16x16x32_bf16(afr, bb[kk & 3][n], acc[n], 0, 0, 0);
            if (kk < 4) {
                #pragma unroll
                for (int n = 0; n < 4; ++n)
                    bb[kk & 3][n] = *reinterpret_cast<const s16x8*>(bp + (size_t)n * 16 * DD + (kk + 4) * 32);
            }
        }

        // ---- epilogue A: biases (hW2 from L2) + LN partial sums ----
        #pragma unroll
        for (int q = 0; q < 4; ++q) {
            const int r = lg * 4 + q;                 // row in tile, 0..15
            const int j = (row_base + r) & 511;
            const float* h2p = hW2 + (size_t)j * DD + w * 64 + l15;
            float s1 = 0.f, s2 = 0.f;
            #pragma unroll
            for (int n = 0; n < 4; ++n) {
                const float v = acc[n][q] + hbn[n] + h2p[n * 16];
                acc[n][q] = v;
                s1 += v;
                s2 = fmaf(v, v, s2);
            }
            #pragma unroll
            for (int s = 1; s < 16; s <<= 1) {
                s1 += __shfl_xor(s1, s, 64);
                s2 += __shfl_xor(s2, s, 64);
            }
            if (l15 == 0) { s_part[r][w][0] = s1; s_part[r][w][1] = s2; }
        }
        LDS_SYNC();   // s_part visible; does NOT drain tile1 DMA

        // ---- epilogue B: stats, normalize, relu, store, gate partials ----
        #pragma unroll
        for (int q = 0; q < 4; ++q) {
            const int r = lg * 4 + q;
            float S1 = 0.f, S2 = 0.f;
            #pragma unroll
            for (int ww = 0; ww < 4; ++ww) { S1 += s_part[r][ww][0]; S2 += s_part[r][ww][1]; }
            const float mu = S1 * (1.f / 256.f);
            const float rs = rsqrtf(S2 * (1.f / 256.f) - mu * mu + 1e-5f);
            const size_t rowg = (size_t)(row_base + r);
            float gl = 0.f;
            #pragma unroll
            for (int n = 0; n < 4; ++n) {
                const int c = w * 64 + n * 16 + l15;
                float v = (acc[n][q] - mu) * rs * s_lnw[c] + s_lnb[c];
                v = fmaxf(v, 0.f);
                acc[n][q] = v;
                out_e[rowg * DD + c] = v;
                gl = fmaf(v, s_gw[c], gl);
            }
            #pragma unroll
            for (int s = 1; s < 16; s <<= 1) gl += __shfl_xor(gl, s, 64);
            if (l15 == 0) s_glog[r][w] = gl;
        }
        LDS_SYNC();   // s_glog visible

        // ---- softmax partials (accumulated across both tiles; same i) ----
        #pragma unroll
        for (int q = 0; q < 4; ++q) {
            const int r = lg * 4 + q;
            const float lv = gb + s_glog[r][0] + s_glog[r][1] + s_glog[r][2] + s_glog[r][3];
            const float ex = __expf(lv);
            zl += ex;
            #pragma unroll
            for (int n = 0; n < 4; ++n) p[n] = fmaf(ex, acc[n][q], p[n]);
        }
    }

    // ---- block tail: reduce p,z over lg; atomic combine (16 blocks/i) ----
    #pragma unroll
    for (int n = 0; n < 4; ++n) {
        p[n] += __shfl_xor(p[n], 16, 64);
        p[n] += __shfl_xor(p[n], 32, 64);
    }
    zl += __shfl_xor(zl, 16, 64);
    zl += __shfl_xor(zl, 32, 64);
    if (lg == 0) {
        #pragma unroll
        for (int n = 0; n < 4; ++n)
            atomicAdd(&wacc[(size_t)i * DD + w * 64 + n * 16 + l15], p[n]);
    }
    if (w == 0 && l == 0) atomicAdd(&zacc[i], zl);
}

// ---------------------------------------------------------------------------
// K4: h_new = h + relu(LN(hW4 + (wacc/z)@W5.T))
// ---------------------------------------------------------------------------
__global__ __launch_bounds__(256) void k4_final(
    const float* __restrict__ wacc, const float* __restrict__ zacc,
    const float* __restrict__ W5,
    const float* __restrict__ hW4, const float* __restrict__ h,
    const float* __restrict__ ln_h_w, const float* __restrict__ ln_h_b,
    float* __restrict__ out_h)
{
    const int i = blockIdx.x;
    const int k = threadIdx.x;
    __shared__ float xs[DD];
    __shared__ float red[256];

    const float zinv = 1.f / zacc[i];
    xs[k] = wacc[(size_t)i * DD + k] * zinv;
    __syncthreads();
    float a = 0.f;
    for (int d = 0; d < DD; ++d) a = fmaf(xs[d], W5[(size_t)k * DD + d], a);
    const float p = hW4[(size_t)i * DD + k] + a;

    red[k] = p;
    __syncthreads();
    for (int s = 128; s > 0; s >>= 1) {
        if (k < s) red[k] += red[k + s];
        __syncthreads();
    }
    const float mu = red[0] * (1.f / 256.f);
    __syncthreads();
    const float d0 = p - mu;
    red[k] = d0 * d0;
    __syncthreads();
    for (int s = 128; s > 0; s >>= 1) {
        if (k < s) red[k] += red[k + s];
        __syncthreads();
    }
    const float rs = rsqrtf(red[0] * (1.f / 256.f) + 1e-5f);
    float v = d0 * rs * ln_h_w[k] + ln_h_b[k];
    v = fmaxf(v, 0.f);
    out_h[(size_t)i * DD + k] = h[(size_t)i * DD + k] + v;
}

// ---------------------------------------------------------------------------
extern "C" void kernel_launch(void* const* d_in, const int* in_sizes, int n_in,
                              void* d_out, int out_size, void* d_ws, size_t ws_size,
                              hipStream_t stream)
{
    const float* h      = (const float*)d_in[0];
    const float* e      = (const float*)d_in[1];
    const float* t_emb  = (const float*)d_in[2];
    const float* W1     = (const float*)d_in[3];
    const float* W2     = (const float*)d_in[4];
    const float* W3     = (const float*)d_in[5];
    const float* W_t    = (const float*)d_in[6];
    const float* W4     = (const float*)d_in[7];
    const float* W5     = (const float*)d_in[8];
    const float* gate_w = (const float*)d_in[9];
    const float* gate_b = (const float*)d_in[10];
    const float* ln_e_w = (const float*)d_in[11];
    const float* ln_e_b = (const float*)d_in[12];
    const float* ln_h_w = (const float*)d_in[13];
    const float* ln_h_b = (const float*)d_in[14];

    float* out_h = (float*)d_out;
    float* out_e = out_h + NN * DD;

    // workspace layout (~2.3 MiB)
    float* wsf  = (float*)d_ws;
    float* hb   = wsf;                        // 131072 (hW1 + t_bias)
    float* hW2  = hb + NN * DD;               // 131072
    float* hW4  = hW2 + NN * DD;              // 131072
    float* wacc = hW4 + NN * DD;              // 131072
    float* zacc = wacc + NN * DD;             // 512
    unsigned short* w3b = (unsigned short*)(zacc + NN);  // 65536 ushort

    k1_pre<<<66, 256, 0, stream>>>(h, W1, W2, W4, t_emb, W_t, W3,
                                   hb, hW2, hW4, w3b, wacc, zacc);
    k2_big<<<8192, 256, 0, stream>>>(e, w3b, hb, hW2, gate_w, gate_b,
                                     ln_e_w, ln_e_b, out_e, wacc, zacc);
    k4_final<<<512, 256, 0, stream>>>(wacc, zacc, W5, hW4, h,
                                      ln_h_w, ln_h_b, out_h);
}